// Round 8
// baseline (16.634 us; speedup 1.0000x reference)
//
#include <hip/hip_runtime.h>
#include <math.h>

#define NN 4096
#define BLK 1024
#define EPT 4

__device__ __forceinline__ void cmul(float& ar, float& ai, float br, float bi) {
    float nr = ar * br - ai * bi;
    float ni = ar * bi + ai * br;
    ar = nr; ai = ni;
}

// new_u = u + i*w ; new_w = w + i*u   (1/sqrt2 folded into theta/phi tables)
__device__ __forceinline__ void bfly_pair(float* vr, float* vi, int a, int b) {
    float ur = vr[a], ui = vi[a], wr = vr[b], wi = vi[b];
    vr[a] = ur - wi; vi[a] = ui + wr;
    vr[b] = wr - ui; vi[b] = wi + ur;
}

// butterflies on the 2 register-resident bits
__device__ __forceinline__ void bfly2(float* vr, float* vi) {
    bfly_pair(vr, vi, 0, 1); bfly_pair(vr, vi, 2, 3);   // bit 0
    bfly_pair(vr, vi, 0, 2); bfly_pair(vr, vi, 1, 3);   // bit 1
}

// element index held by (t, r) at residency P (register bits P..P+1)
template<int P>
__device__ __forceinline__ int jidx(int t, int r) {
    return ((t >> P) << (P + 2)) | (r << P) | (t & ((1 << P) - 1));
}

// XOR swizzle: jj = j ^ (5 * ((j>>4)&3)) — injects j[5:4] into both low bit-pairs.
// Verified bijective mod 16 per 16-lane group for P = 0,2,4,6,8,10 (b64 floor,
// zero conflicts); touches only j[3:0] so wave-slice ownership is preserved.
__device__ __forceinline__ int swz(int j) { return j ^ (((j >> 4) & 3) * 5); }

template<int P>
__device__ __forceinline__ void wrt(float2* buf, const float* vr, const float* vi, int t) {
    #pragma unroll
    for (int r = 0; r < EPT; ++r) {
        int j = jidx<P>(t, r);
        buf[swz(j)] = make_float2(vr[r], vi[r]);
    }
}

template<int P>
__device__ __forceinline__ void rd(const float2* buf, float* vr, float* vi, int t) {
    #pragma unroll
    for (int r = 0; r < EPT; ++r) {
        int j = jidx<P>(t, r);
        float2 v = buf[swz(j)];
        vr[r] = v.x; vi[r] = v.y;
    }
}

__global__ __launch_bounds__(BLK) void qubit_layer_kernel(
    const float* __restrict__ x,
    const float* __restrict__ alphas, const float* __restrict__ betas,
    const float* __restrict__ thetas, const float* __restrict__ phis,
    float* __restrict__ out)
{
    __shared__ float2 S[NN];        // 32 KB exchange buffer (xor-swizzled)
    __shared__ float2 tbl[6][64];   // 0=in_lo 1=in_hi 2=th_lo(/64) 3=th_hi 4=ph_lo(/64) 5=ph_hi

    const int t = threadIdx.x;
    const int b = blockIdx.x;

    // ---- issue global loads early (P=0 layout: j = 4t + r) ----
    const float* xr = x + (size_t)b * 2 * NN;
    const float* xi = xr + NN;
    float4 La = *(const float4*)(xr + t * EPT);
    float4 Lb = *(const float4*)(xi + t * EPT);

    // ---- build phase tables (overlaps the loads) ----
    if (t < 384) {
        int part = t >> 6, idx = t & 63, set = part >> 1, half = part & 1;
        float a = 0.f;
        #pragma unroll
        for (int m = 0; m < 6; ++m) {
            int q = half ? m : (6 + m);
            int bit = (idx >> (5 - m)) & 1;
            float av, bv;
            if (set == 0)      { av = alphas[q]; bv = betas[q]; }
            else if (set == 1) { av = thetas[q]; bv = 0.f; }
            else               { av = phis[q];   bv = 0.f; }
            a += bit ? bv : av;
        }
        float s, c;
        __sincosf(a, &s, &c);
        float sc = (set >= 1 && half == 0) ? (1.0f / 64.0f) : 1.0f;
        tbl[part][idx] = make_float2(c * sc, s * sc);
    }
    __syncthreads();   // tables ready

    float vr[EPT], vi[EPT];
    vr[0]=La.x; vr[1]=La.y; vr[2]=La.z; vr[3]=La.w;
    vi[0]=Lb.x; vi[1]=Lb.y; vi[2]=Lb.z; vi[3]=Lb.w;

    // ---- D_in at P=0: j = 4t+r -> l = (t&15)*4 + r, h = t>>4 ----
    {
        float2 eh = tbl[1][t >> 4];
        const float4* elv = (const float4*)&tbl[0][(t & 15) << 2];
        #pragma unroll
        for (int k = 0; k < 2; ++k) {
            float4 e2 = elv[k];
            float er0 = e2.x, ei0 = e2.y, er1 = e2.z, ei1 = e2.w;
            cmul(er0, ei0, eh.x, eh.y);
            cmul(er1, ei1, eh.x, eh.y);
            cmul(vr[2*k],   vi[2*k],   er0, ei0);
            cmul(vr[2*k+1], vi[2*k+1], er1, ei1);
        }
    }

    // ---- BS1: up-ladder 0-1 | 2-3 | 4-5 | 6-7 | 8-9 | 10-11 ----
    bfly2(vr, vi);
    wrt<0>(S, vr, vi, t); asm volatile("" ::: "memory"); rd<2>(S, vr, vi, t);
    bfly2(vr, vi);
    wrt<2>(S, vr, vi, t); asm volatile("" ::: "memory"); rd<4>(S, vr, vi, t);
    bfly2(vr, vi);
    wrt<4>(S, vr, vi, t); asm volatile("" ::: "memory"); rd<6>(S, vr, vi, t);
    bfly2(vr, vi);
    wrt<6>(S, vr, vi, t); __syncthreads(); rd<8>(S, vr, vi, t);
    bfly2(vr, vi);
    wrt<8>(S, vr, vi, t); __syncthreads(); rd<10>(S, vr, vi, t);
    bfly2(vr, vi);

    // ---- D_theta at P=10 (j = r*1024 + t): l = t&63, h = (r<<4)|(t>>6) ----
    {
        float2 el = tbl[2][t & 63];
        #pragma unroll
        for (int r = 0; r < EPT; ++r) {
            float2 eh = tbl[3][(r << 4) | (t >> 6)];
            float er = el.x, ei = el.y;
            cmul(er, ei, eh.x, eh.y);
            cmul(vr[r], vi[r], er, ei);
        }
    }

    // ---- BS2: down-ladder 10-11 | 8-9 | 6-7 | 4-5 | 2-3 | 0-1 ----
    bfly2(vr, vi);
    wrt<10>(S, vr, vi, t); __syncthreads(); rd<8>(S, vr, vi, t);
    bfly2(vr, vi);
    wrt<8>(S, vr, vi, t); __syncthreads(); rd<6>(S, vr, vi, t);
    bfly2(vr, vi);
    wrt<6>(S, vr, vi, t); asm volatile("" ::: "memory"); rd<4>(S, vr, vi, t);
    bfly2(vr, vi);
    wrt<4>(S, vr, vi, t); asm volatile("" ::: "memory"); rd<2>(S, vr, vi, t);
    bfly2(vr, vi);
    wrt<2>(S, vr, vi, t); asm volatile("" ::: "memory"); rd<0>(S, vr, vi, t);
    bfly2(vr, vi);

    // ---- D_phi at P=0 + float4 stores ----
    {
        float2 eh = tbl[5][t >> 4];
        const float4* elv = (const float4*)&tbl[4][(t & 15) << 2];
        #pragma unroll
        for (int k = 0; k < 2; ++k) {
            float4 e2 = elv[k];
            float er0 = e2.x, ei0 = e2.y, er1 = e2.z, ei1 = e2.w;
            cmul(er0, ei0, eh.x, eh.y);
            cmul(er1, ei1, eh.x, eh.y);
            cmul(vr[2*k],   vi[2*k],   er0, ei0);
            cmul(vr[2*k+1], vi[2*k+1], er1, ei1);
        }
    }
    float* outr = out + (size_t)b * 2 * NN;
    float* outi = outr + NN;
    *(float4*)(outr + t * EPT) = make_float4(vr[0], vr[1], vr[2], vr[3]);
    *(float4*)(outi + t * EPT) = make_float4(vi[0], vi[1], vi[2], vi[3]);
}

extern "C" void kernel_launch(void* const* d_in, const int* in_sizes, int n_in,
                              void* d_out, int out_size, void* d_ws, size_t ws_size,
                              hipStream_t stream) {
    const float* x      = (const float*)d_in[0];
    const float* alphas = (const float*)d_in[1];
    const float* betas  = (const float*)d_in[2];
    const float* thetas = (const float*)d_in[3];
    const float* phis   = (const float*)d_in[4];
    float* out = (float*)d_out;

    const int batch = in_sizes[0] / (2 * NN);   // 64
    qubit_layer_kernel<<<batch, BLK, 0, stream>>>(x, alphas, betas, thetas, phis, out);
}

// Round 9
// 10.749 us; speedup vs baseline: 1.5475x; 1.5475x over previous
//
#include <hip/hip_runtime.h>
#include <math.h>

#define NN 4096
#define BLK 512
#define EPT 8

__device__ __forceinline__ void cmul(float& ar, float& ai, float br, float bi) {
    float nr = ar * br - ai * bi;
    float ni = ar * bi + ai * br;
    ar = nr; ai = ni;
}

// new_u = u + i*w ; new_w = w + i*u  (1/sqrt2 folded into theta/phi tables)
__device__ __forceinline__ void bfly_pair(float* vr, float* vi, int a, int b) {
    float ur = vr[a], ui = vi[a], wr = vr[b], wi = vi[b];
    vr[a] = ur - wi; vi[a] = ui + wr;
    vr[b] = wr - ui; vi[b] = wi + ur;
}

__device__ __forceinline__ void bfly3(float* vr, float* vi) {
    bfly_pair(vr, vi, 0, 1); bfly_pair(vr, vi, 2, 3); bfly_pair(vr, vi, 4, 5); bfly_pair(vr, vi, 6, 7);
    bfly_pair(vr, vi, 0, 2); bfly_pair(vr, vi, 1, 3); bfly_pair(vr, vi, 4, 6); bfly_pair(vr, vi, 5, 7);
    bfly_pair(vr, vi, 0, 4); bfly_pair(vr, vi, 1, 5); bfly_pair(vr, vi, 2, 6); bfly_pair(vr, vi, 3, 7);
}

template<int P>
__device__ __forceinline__ int jidx(int t, int r) {
    return ((t >> P) << (P + 3)) | (r << P) | (t & ((1 << P) - 1));
}

// Swizzle for u32 (bf16x2) slots: S[4:0] = j[4:0]^j[9:5], S[4]^=j[6].
// Rank-5 over lane bits for P=0,3,6,9 -> exactly 2 lanes/bank (free).
// Preserves j[11:5] -> wave-slice ownership identical to the fp32 version.
__device__ __forceinline__ int swz(int j) {
    return j ^ ((j >> 5) & 31) ^ (((j >> 6) & 1) << 4);
}

// bf16 RNE pack/unpack (hand-rolled, finite values only)
__device__ __forceinline__ unsigned bfr(float f) {
    unsigned u = __float_as_uint(f);
    return (u + 0x7fffu + ((u >> 16) & 1u)) >> 16;
}
__device__ __forceinline__ unsigned packc(float re, float im) {
    return bfr(re) | (bfr(im) << 16);
}
__device__ __forceinline__ float unlo(unsigned v) { return __uint_as_float(v << 16); }
__device__ __forceinline__ float unhi(unsigned v) { return __uint_as_float(v & 0xffff0000u); }

// Exchange register-bit block PC -> PN through LDS (bf16x2 packed).
// CROSS=false: wave-private slice (per-wave DS ordering + compiler fence).
template<int PC, int PN, bool CROSS>
__device__ __forceinline__ void exchange(unsigned* buf, float* vr, float* vi, int t) {
    #pragma unroll
    for (int r = 0; r < EPT; ++r) {
        buf[swz(jidx<PC>(t, r))] = packc(vr[r], vi[r]);
    }
    if (CROSS) { __syncthreads(); }
    else       { asm volatile("" ::: "memory"); }
    #pragma unroll
    for (int r = 0; r < EPT; ++r) {
        unsigned v = buf[swz(jidx<PN>(t, r))];
        vr[r] = unlo(v); vi[r] = unhi(v);
    }
}

__global__ __launch_bounds__(BLK) void qubit_layer_kernel(
    const float* __restrict__ x,
    const float* __restrict__ alphas, const float* __restrict__ betas,
    const float* __restrict__ thetas, const float* __restrict__ phis,
    float* __restrict__ out)
{
    __shared__ unsigned S1[NN];     // 16 KB
    __shared__ unsigned S2[NN];     // 16 KB
    __shared__ float2 tbl[6][64];   // 0=in_lo 1=in_hi 2=th_lo(/64) 3=th_hi 4=ph_lo(/64) 5=ph_hi

    const int t = threadIdx.x;
    const int b = blockIdx.x;

    // ---- issue global loads FIRST (P=0 layout: j = 8t + r) ----
    const float* xr = x + (size_t)b * 2 * NN;
    const float* xi = xr + NN;
    float4 a0 = ((const float4*)(xr + t * EPT))[0];
    float4 a1 = ((const float4*)(xr + t * EPT))[1];
    float4 c0 = ((const float4*)(xi + t * EPT))[0];
    float4 c1 = ((const float4*)(xi + t * EPT))[1];

    // ---- build phase tables (1 sincos per builder thread) ----
    if (t < 384) {
        int part = t >> 6, idx = t & 63, set = part >> 1, half = part & 1;
        float a = 0.f;
        #pragma unroll
        for (int m = 0; m < 6; ++m) {
            int q = half ? m : (6 + m);
            int bit = (idx >> (5 - m)) & 1;
            float av, bv;
            if (set == 0)      { av = alphas[q]; bv = betas[q]; }
            else if (set == 1) { av = thetas[q]; bv = 0.f; }
            else               { av = phis[q];   bv = 0.f; }
            a += bit ? bv : av;
        }
        float s, c;
        __sincosf(a, &s, &c);
        float sc = (set >= 1 && half == 0) ? (1.0f / 64.0f) : 1.0f;
        tbl[part][idx] = make_float2(c * sc, s * sc);
    }

    float vr[EPT], vi[EPT];
    vr[0]=a0.x; vr[1]=a0.y; vr[2]=a0.z; vr[3]=a0.w; vr[4]=a1.x; vr[5]=a1.y; vr[6]=a1.z; vr[7]=a1.w;
    vi[0]=c0.x; vi[1]=c0.y; vi[2]=c0.z; vi[3]=c0.w; vi[4]=c1.x; vi[5]=c1.y; vi[6]=c1.z; vi[7]=c1.w;

    __syncthreads();   // tables ready

    // ---- D_in at P=0: l = (t&7)*8 + r (b128 table reads), h = t>>3 (broadcast) ----
    {
        float2 eh = tbl[1][t >> 3];
        const float4* elv = (const float4*)&tbl[0][(t & 7) << 3];
        #pragma unroll
        for (int k = 0; k < 4; ++k) {
            float4 e2 = elv[k];
            float er0 = e2.x, ei0 = e2.y, er1 = e2.z, ei1 = e2.w;
            cmul(er0, ei0, eh.x, eh.y);
            cmul(er1, ei1, eh.x, eh.y);
            cmul(vr[2*k],   vi[2*k],   er0, ei0);
            cmul(vr[2*k+1], vi[2*k+1], er1, ei1);
        }
    }

    // ---- BS1: bits 0-2 | 3-5 | 6-8 | 9-11 ----
    bfly3(vr, vi);
    exchange<0, 3, false>(S1, vr, vi, t); bfly3(vr, vi);
    exchange<3, 6, false>(S1, vr, vi, t); bfly3(vr, vi);
    exchange<6, 9, true >(S1, vr, vi, t); bfly3(vr, vi);

    // ---- D_theta at P=9 (j = r*512 + t): l = t&63, h = (t>>6) + 8r ----
    {
        float2 el = tbl[2][t & 63];
        #pragma unroll
        for (int r = 0; r < EPT; ++r) {
            float2 eh = tbl[3][(t >> 6) + (r << 3)];
            float er = el.x, ei = el.y;
            cmul(er, ei, eh.x, eh.y);
            cmul(vr[r], vi[r], er, ei);
        }
    }

    // ---- BS2 down-ladder: bits 9-11 | 6-8 | 3-5 | 0-2 ----
    bfly3(vr, vi);
    exchange<9, 6, true >(S2, vr, vi, t); bfly3(vr, vi);
    exchange<6, 3, false>(S1, vr, vi, t); bfly3(vr, vi);
    exchange<3, 0, false>(S1, vr, vi, t); bfly3(vr, vi);

    // ---- D_phi at P=0 + float4 stores ----
    {
        float2 eh = tbl[5][t >> 3];
        const float4* elv = (const float4*)&tbl[4][(t & 7) << 3];
        #pragma unroll
        for (int k = 0; k < 4; ++k) {
            float4 e2 = elv[k];
            float er0 = e2.x, ei0 = e2.y, er1 = e2.z, ei1 = e2.w;
            cmul(er0, ei0, eh.x, eh.y);
            cmul(er1, ei1, eh.x, eh.y);
            cmul(vr[2*k],   vi[2*k],   er0, ei0);
            cmul(vr[2*k+1], vi[2*k+1], er1, ei1);
        }
    }
    float* outr = out + (size_t)b * 2 * NN;
    float* outi = outr + NN;
    ((float4*)(outr + t * EPT))[0] = make_float4(vr[0], vr[1], vr[2], vr[3]);
    ((float4*)(outr + t * EPT))[1] = make_float4(vr[4], vr[5], vr[6], vr[7]);
    ((float4*)(outi + t * EPT))[0] = make_float4(vi[0], vi[1], vi[2], vi[3]);
    ((float4*)(outi + t * EPT))[1] = make_float4(vi[4], vi[5], vi[6], vi[7]);
}

extern "C" void kernel_launch(void* const* d_in, const int* in_sizes, int n_in,
                              void* d_out, int out_size, void* d_ws, size_t ws_size,
                              hipStream_t stream) {
    const float* x      = (const float*)d_in[0];
    const float* alphas = (const float*)d_in[1];
    const float* betas  = (const float*)d_in[2];
    const float* thetas = (const float*)d_in[3];
    const float* phis   = (const float*)d_in[4];
    float* out = (float*)d_out;

    const int batch = in_sizes[0] / (2 * NN);   // 64
    qubit_layer_kernel<<<batch, BLK, 0, stream>>>(x, alphas, betas, thetas, phis, out);
}